// Round 8
// baseline (467.988 us; speedup 1.0000x reference)
//
#include <hip/hip_runtime.h>
#include <cstdint>
#include <cstddef>

#define B 4096
#define S 200
#define V 33
#define T 50
#define EPSV 1e-08

#define NLLB 256                    // NLL blocks, 16 batch rows each (at grid end)
#define GRID (B + NLLB)             // sweep block b = blk for blk < B

// ws layout:
// [0]      double ll_part[B]      32 KiB
// [32768]  int    lenm1[B]        16 KiB
// [49152]  double nll_part[NLLB]   2 KiB
// [51200]  int    done             4 B   (hipMemsetAsync -> 0 each call)
// Every slot is written by its owning block each call; final reduce is done
// by exactly one (the last-finishing) block -> deterministic output.

using f4  = __attribute__((ext_vector_type(4))) float;
using f4u = __attribute__((aligned(4))) f4;          // 4B-aligned float4 view

__device__ __forceinline__ bool is_nan_bits(float x) {
    uint32_t u = __float_as_uint(x);
    return (u & 0x7F800000u) == 0x7F800000u && (u & 0x007FFFFFu) != 0u;
}

// Clamped flat float4 sweep batch with NaN masking.
// lp vec k covers floats j=4k..4k+3 (lp row k>>3); matching data floats at
// j + (k>>3) + 34 (cols 1..32 of row (k>>3)+1). Rows past len are all-NaN:
// zero their diffs; count valid rows via the (k&7)==0 vec's first element.
template <int D>
__device__ __forceinline__ void sweep_batch(const float* __restrict__ lpbase,
                                            const float* __restrict__ dbase,
                                            int k0, int nvec,
                                            float& acc, int& cnt) {
    f4 lpv[D], dv[D];
    #pragma unroll
    for (int u = 0; u < D; ++u) {
        int k  = k0 + u * 256;
        int kc = k < nvec ? k : (nvec - 1);
        int j  = kc * 4;
        int sr = kc >> 3;
        lpv[u] = *reinterpret_cast<const f4*>(lpbase + j);
        dv[u]  = *reinterpret_cast<const f4u*>(dbase + j + sr + 34);
    }
    #pragma unroll
    for (int u = 0; u < D; ++u) {
        int k = k0 + u * 256;
        if (k < nvec) {
            #pragma unroll
            for (int i = 0; i < 4; ++i) {
                float de = dv[u][i];
                float df = lpv[u][i] - de;
                if (is_nan_bits(de)) df = 0.0f;
                acc = fmaf(df, df, acc);
            }
            if ((k & 7) == 0 && !is_nan_bits(dv[u][0])) cnt++;
        }
    }
}

__global__ __launch_bounds__(256, 4)
void fused_kernel(const float* __restrict__ long_pred,
                  const float* __restrict__ surv_pred,
                  const float* __restrict__ data,
                  const uint32_t* __restrict__ event_words,
                  const float* __restrict__ event_time,
                  const float* __restrict__ time_range,
                  double* __restrict__ ll_part,
                  int* __restrict__ lenm1,
                  double* __restrict__ nll_part,
                  int* __restrict__ done,
                  float* __restrict__ out) {
    const int tid  = threadIdx.x;
    const int blk  = blockIdx.x;
    const int wib  = tid >> 6;
    const int lane = tid & 63;

    if (blk < B) {
        // ---------------- longitudinal sweep: one batch row per block --------
        const int b = blk;
        const float* __restrict__ dbase  = data      + (size_t)b * (S * V);
        const float* __restrict__ lpbase = long_pred + (size_t)b * (S * (V - 1));

        // one probe round: threads 0..49 test row 4t+3 col 1 (prefix validity)
        int valid = 0;
        if (tid < 50) valid = !is_nan_bits(dbase[(size_t)(4 * tid + 3) * V + 1]);
        const int c1 = __syncthreads_count(valid);       // = #valid probes
        const int bound_rows = min(4 * c1 + 2, S - 1);   // >= len-1, <= len+2
        const int nvec = bound_rows * 8;                 // <= 1592

        float acc = 0.0f;
        int   cnt = 0;
        sweep_batch<4>(lpbase, dbase, tid, nvec, acc, cnt);            // k<1024
        if (nvec > 1024)
            sweep_batch<3>(lpbase, dbase, tid + 1024, nvec, acc, cnt); // k<1792

        for (int off = 32; off > 0; off >>= 1) {
            acc += __shfl_down(acc, off);
            cnt += __shfl_down(cnt, off);
        }
        __shared__ float s_red[4];
        __shared__ int   s_cnt[4];
        if (lane == 0) { s_red[wib] = acc; s_cnt[wib] = cnt; }
        __syncthreads();
        if (tid == 0) {
            ll_part[b] = (double)s_red[0] + (double)s_red[1]
                       + (double)s_red[2] + (double)s_red[3];
            lenm1[b]   = s_cnt[0] + s_cnt[1] + s_cnt[2] + s_cnt[3];
        }
    } else {
        // ---------------- survival NLL: 16 batch rows per block --------------
        const int nb = blk - B;

        // event storage detect (scan exactly B bytes: safe in all layouts)
        __shared__ int s_gt1, s_oddnz;
        if (tid == 0) { s_gt1 = 0; s_oddnz = 0; }
        __syncthreads();
        int gt1 = 0, oddnz = 0;
        for (int i = tid; i < B / 4; i += 256) {
            uint32_t w = event_words[i];
            if (w > 1u) gt1 = 1;
            if ((i & 1) && w != 0u) oddnz = 1;
        }
        if (gt1)   atomicOr(&s_gt1, 1);
        if (oddnz) atomicOr(&s_oddnz, 1);
        __syncthreads();
        const int mode = s_gt1 ? 1 : (s_oddnz ? 0 : 2);  // 1=u8, 0=i32, 2=i64

        double nsum = 0.0;
        #pragma unroll
        for (int r = 0; r < 4; ++r) {
            const int b = nb * 16 + r * 4 + wib;
            float sv = (lane < T) ? surv_pred[b * T + lane] : 0.0f;
            float tr = (lane < T) ? time_range[lane] : 0.0f;
            float et = event_time[b];

            // searchsorted(time_range, et, 'right') - 1
            unsigned long long bal = __ballot(lane < T && tr <= et);
            int idx = (int)__popcll(bal) - 1;

            // tail = sum_{t >= idx+1} surv_pred[b,t]
            float tval = (lane < T && lane >= idx + 1) ? sv : 0.0f;
            for (int off = 32; off > 0; off >>= 1) tval += __shfl_down(tval, off);

            int   idx_c  = idx < 0 ? 0 : idx;
            float at_idx = __shfl(sv, idx_c);

            bool ev;
            if (mode == 1)      ev = ((const unsigned char*)event_words)[b] != 0;
            else if (mode == 2) ev = ((const int*)event_words)[2 * b] != 0;
            else                ev = ((const int*)event_words)[b] != 0;

            if (lane == 0) {
                float f = ev ? at_idx : ((idx + 1 < T) ? tval : 0.0f);
                if (f == 0.0f) f = (float)EPSV;
                nsum += -(double)logf(f);
            }
        }

        __shared__ double s_n[4];
        if (lane == 0) s_n[wib] = nsum;
        __syncthreads();
        if (tid == 0) nll_part[nb] = s_n[0] + s_n[1] + s_n[2] + s_n[3];
    }

    // ---------------- last-finishing block reduces everything ----------------
    __shared__ int s_last;
    __threadfence();                               // release our slot writes
    if (tid == 0) s_last = (atomicAdd(done, 1) == GRID - 1);
    __syncthreads();
    if (!s_last) return;
    __threadfence();                               // acquire others' writes

    double ls = 0.0, ns = 0.0;
    long long cs = 0;
    for (int i = tid; i < B; i += 256)    { ls += ll_part[i]; cs += lenm1[i]; }
    for (int i = tid; i < NLLB; i += 256) ns += nll_part[i];

    for (int off = 32; off > 0; off >>= 1) {
        ls += __shfl_down(ls, off);
        ns += __shfl_down(ns, off);
        cs += __shfl_down(cs, off);
    }
    __shared__ double    sl[4], sn[4];
    __shared__ long long sc[4];
    if (lane == 0) { sl[wib] = ls; sn[wib] = ns; sc[wib] = cs; }
    __syncthreads();
    if (tid == 0) {
        double L = 0.0, N = 0.0;
        long long C = 0;
        for (int i = 0; i < 4; ++i) { L += sl[i]; N += sn[i]; C += sc[i]; }
        double denom = (double)C * (double)(V - 1);
        out[0] = (float)(N / (double)B + L / denom);
    }
}

extern "C" void kernel_launch(void* const* d_in, const int* in_sizes, int n_in,
                              void* d_out, int out_size, void* d_ws, size_t ws_size,
                              hipStream_t stream) {
    const float* long_pred  = (const float*)d_in[0];
    const float* surv_pred  = (const float*)d_in[1];
    const float* data       = (const float*)d_in[2];
    const void*  event      = d_in[3];
    const float* event_time = (const float*)d_in[4];
    const float* time_range = (const float*)d_in[5];
    float* out = (float*)d_out;

    double* ll_part  = (double*)d_ws;
    int*    lenm1    = (int*)((char*)d_ws + 32768);
    double* nll_part = (double*)((char*)d_ws + 49152);
    int*    done     = (int*)((char*)d_ws + 51200);

    hipMemsetAsync(done, 0, 4, stream);
    fused_kernel<<<GRID, 256, 0, stream>>>(
        long_pred, surv_pred, data, (const uint32_t*)event, event_time,
        time_range, ll_part, lenm1, nll_part, done, out);
}

// Round 9
// 36.161 us; speedup vs baseline: 12.9418x; 12.9418x over previous
//
#include <hip/hip_runtime.h>
#include <cstdint>
#include <cstddef>

#define B 4096
#define S 200
#define V 33
#define T 50
#define EPSV 1e-08

#define NLLB 128                    // NLL blocks, 32 batch rows each (grid tail)
#define GRID (B + NLLB)             // sweep block b = blk for blk < B

// ws layout:
// [0]      double ll_part[B]      32 KiB
// [32768]  int    lenm1[B]        16 KiB
// [49152]  double nll_part[NLLB]   1 KiB
// Every slot is unconditionally written by its owning block each call:
// no memset node, no fences, poison/replay-safe, deterministic.

using f4  = __attribute__((ext_vector_type(4))) float;
using f4u = __attribute__((aligned(4))) f4;          // 4B-aligned float4 view

__device__ __forceinline__ bool is_nan_bits(float x) {
    uint32_t u = __float_as_uint(x);
    return (u & 0x7F800000u) == 0x7F800000u && (u & 0x007FFFFFu) != 0u;
}

// lp vec k covers floats j=4k..4k+3 (lp row k>>3); matching data floats at
// j + (k>>3) + 34 (cols 1..32 of row (k>>3)+1). Rows past len are all-NaN.
template <int D, bool CLAMP>
__device__ __forceinline__ void issue_loads(const float* __restrict__ lpbase,
                                            const float* __restrict__ dbase,
                                            int k0, int nvec, f4* lpv, f4* dv) {
    #pragma unroll
    for (int u = 0; u < D; ++u) {
        int k  = k0 + u * 256;
        int kc = CLAMP ? (k < nvec ? k : nvec - 1) : k;
        int j  = kc * 4;
        int sr = kc >> 3;
        lpv[u] = *reinterpret_cast<const f4*>(lpbase + j);
        dv[u]  = *reinterpret_cast<const f4u*>(dbase + j + sr + 34);
    }
}

// NaN-masked accumulate; counts valid rows via the (k&7)==0 vec's elem 0.
template <int D, bool GUARD>
__device__ __forceinline__ void accum(const f4* lpv, const f4* dv,
                                      int k0, int nvec, float& acc, int& cnt) {
    #pragma unroll
    for (int u = 0; u < D; ++u) {
        int k = k0 + u * 256;
        if (!GUARD || k < nvec) {
            #pragma unroll
            for (int i = 0; i < 4; ++i) {
                float de = dv[u][i];
                float df = lpv[u][i] - de;
                if (is_nan_bits(de)) df = 0.0f;
                acc = fmaf(df, df, acc);
            }
            if ((k & 7) == 0 && !is_nan_bits(dv[u][0])) cnt++;
        }
    }
}

__global__ __launch_bounds__(256, 4)
void fused_kernel(const float* __restrict__ long_pred,
                  const float* __restrict__ surv_pred,
                  const float* __restrict__ data,
                  const uint32_t* __restrict__ event_words,
                  const float* __restrict__ event_time,
                  const float* __restrict__ time_range,
                  double* __restrict__ ll_part,
                  int* __restrict__ lenm1,
                  double* __restrict__ nll_part) {
    const int tid  = threadIdx.x;
    const int blk  = blockIdx.x;
    const int wib  = tid >> 6;
    const int lane = tid & 63;

    if (blk < B) {
        // ---------------- longitudinal sweep: one batch row per block --------
        const int b = blk;
        const float* __restrict__ dbase  = data      + (size_t)b * (S * V);
        const float* __restrict__ lpbase = long_pred + (size_t)b * (S * (V - 1));

        // batch 1 (k<512, rows<64): address-safe for ANY len, NaN-masked.
        // Issue its loads BEFORE the probe barrier so streaming starts now.
        f4 lp1[2], d1[2];
        issue_loads<2, false>(lpbase, dbase, tid, 0, lp1, d1);

        // probe: threads 0..49 test row 4t+3 col 1 (validity is a prefix)
        int valid = 0;
        if (tid < 50) valid = !is_nan_bits(dbase[(size_t)(4 * tid + 3) * V + 1]);
        const int c1 = __syncthreads_count(valid);       // = #valid probes
        const int bound_rows = min(4 * c1 + 2, S - 1);   // >= len-1, <= len+2
        const int nvec = bound_rows * 8;                 // <= 1592

        float acc = 0.0f;
        int   cnt = 0;
        accum<2, false>(lp1, d1, tid, 0, acc, cnt);

        if (nvec > 512) {                                // k in [512,1024)
            f4 lp2[2], d2[2];
            issue_loads<2, true>(lpbase, dbase, tid + 512, nvec, lp2, d2);
            accum<2, true>(lp2, d2, tid + 512, nvec, acc, cnt);
        }
        if (nvec > 1024) {                               // k in [1024,1592)
            f4 lp3[3], d3[3];
            issue_loads<3, true>(lpbase, dbase, tid + 1024, nvec, lp3, d3);
            accum<3, true>(lp3, d3, tid + 1024, nvec, acc, cnt);
        }

        for (int off = 32; off > 0; off >>= 1) {
            acc += __shfl_down(acc, off);
            cnt += __shfl_down(cnt, off);
        }
        __shared__ float s_red[4];
        __shared__ int   s_cnt[4];
        if (lane == 0) { s_red[wib] = acc; s_cnt[wib] = cnt; }
        __syncthreads();
        if (tid == 0) {
            ll_part[b] = (double)s_red[0] + (double)s_red[1]
                       + (double)s_red[2] + (double)s_red[3];
            lenm1[b]   = s_cnt[0] + s_cnt[1] + s_cnt[2] + s_cnt[3];
        }
    } else {
        // ---------------- survival NLL: 32 batch rows per block --------------
        const int nb = blk - B;

        // event storage detect (scan exactly B bytes: safe in all layouts)
        __shared__ int s_gt1, s_oddnz;
        if (tid == 0) { s_gt1 = 0; s_oddnz = 0; }
        __syncthreads();
        int gt1 = 0, oddnz = 0;
        for (int i = tid; i < B / 4; i += 256) {
            uint32_t w = event_words[i];
            if (w > 1u) gt1 = 1;
            if ((i & 1) && w != 0u) oddnz = 1;
        }
        if (gt1)   atomicOr(&s_gt1, 1);
        if (oddnz) atomicOr(&s_oddnz, 1);
        __syncthreads();
        const int mode = s_gt1 ? 1 : (s_oddnz ? 0 : 2);  // 1=u8, 0=i32, 2=i64

        double nsum = 0.0;
        #pragma unroll
        for (int r = 0; r < 8; ++r) {
            const int b = nb * 32 + r * 4 + wib;
            float sv = (lane < T) ? surv_pred[b * T + lane] : 0.0f;
            float tr = (lane < T) ? time_range[lane] : 0.0f;
            float et = event_time[b];

            // searchsorted(time_range, et, 'right') - 1
            unsigned long long bal = __ballot(lane < T && tr <= et);
            int idx = (int)__popcll(bal) - 1;

            // tail = sum_{t >= idx+1} surv_pred[b,t]
            float tval = (lane < T && lane >= idx + 1) ? sv : 0.0f;
            for (int off = 32; off > 0; off >>= 1) tval += __shfl_down(tval, off);

            int   idx_c  = idx < 0 ? 0 : idx;
            float at_idx = __shfl(sv, idx_c);

            bool ev;
            if (mode == 1)      ev = ((const unsigned char*)event_words)[b] != 0;
            else if (mode == 2) ev = ((const int*)event_words)[2 * b] != 0;
            else                ev = ((const int*)event_words)[b] != 0;

            if (lane == 0) {
                float f = ev ? at_idx : ((idx + 1 < T) ? tval : 0.0f);
                if (f == 0.0f) f = (float)EPSV;
                nsum += -(double)logf(f);
            }
        }

        __shared__ double s_n[4];
        if (lane == 0) s_n[wib] = nsum;
        __syncthreads();
        if (tid == 0) nll_part[nb] = s_n[0] + s_n[1] + s_n[2] + s_n[3];
    }
}

__global__ __launch_bounds__(256)
void finalize_kernel(const double* __restrict__ ll_part,
                     const int* __restrict__ lenm1,
                     const double* __restrict__ nll_part,
                     float* __restrict__ out) {
    const int tid = threadIdx.x;
    double ls = 0.0, ns = 0.0;
    long long cs = 0;
    for (int i = tid; i < B; i += 256)    { ls += ll_part[i]; cs += lenm1[i]; }
    if (tid < NLLB) ns = nll_part[tid];

    for (int off = 32; off > 0; off >>= 1) {
        ls += __shfl_down(ls, off);
        ns += __shfl_down(ns, off);
        cs += __shfl_down(cs, off);
    }
    __shared__ double    sl[4], sn[4];
    __shared__ long long sc[4];
    const int wib = tid >> 6, lane = tid & 63;
    if (lane == 0) { sl[wib] = ls; sn[wib] = ns; sc[wib] = cs; }
    __syncthreads();
    if (tid == 0) {
        double L = 0.0, N = 0.0;
        long long C = 0;
        for (int i = 0; i < 4; ++i) { L += sl[i]; N += sn[i]; C += sc[i]; }
        double denom = (double)C * (double)(V - 1);
        out[0] = (float)(N / (double)B + L / denom);
    }
}

extern "C" void kernel_launch(void* const* d_in, const int* in_sizes, int n_in,
                              void* d_out, int out_size, void* d_ws, size_t ws_size,
                              hipStream_t stream) {
    const float* long_pred  = (const float*)d_in[0];
    const float* surv_pred  = (const float*)d_in[1];
    const float* data       = (const float*)d_in[2];
    const void*  event      = d_in[3];
    const float* event_time = (const float*)d_in[4];
    const float* time_range = (const float*)d_in[5];
    float* out = (float*)d_out;

    double* ll_part  = (double*)d_ws;
    int*    lenm1    = (int*)((char*)d_ws + 32768);
    double* nll_part = (double*)((char*)d_ws + 49152);

    fused_kernel<<<GRID, 256, 0, stream>>>(
        long_pred, surv_pred, data, (const uint32_t*)event, event_time,
        time_range, ll_part, lenm1, nll_part);
    finalize_kernel<<<1, 256, 0, stream>>>(ll_part, lenm1, nll_part, out);
}

// Round 10
// 31.354 us; speedup vs baseline: 14.9260x; 1.1533x over previous
//
#include <hip/hip_runtime.h>
#include <cstdint>
#include <cstddef>

#define B 4096
#define S 200
#define V 33
#define T 50
#define EPSV 1e-08

#define NLLB 1024                 // NLL blocks (4 batch rows each), blk < NLLB
#define GRID (NLLB + B)           // sweep block for b = blk - NLLB

// ws layout:
// [0]      double ll_part[B]     32 KiB
// [32768]  int    lenm1[B]       16 KiB
// [49152]  double nll_part[NLLB]  8 KiB
// Every slot is unconditionally written by its owning block each call:
// no memset node, no fences, poison/replay-safe, deterministic.

using f4  = __attribute__((ext_vector_type(4))) float;
using f4u = __attribute__((aligned(4))) f4;          // 4B-aligned float4 view

__device__ __forceinline__ bool is_nan_bits(float x) {
    uint32_t u = __float_as_uint(x);
    return (u & 0x7F800000u) == 0x7F800000u && (u & 0x007FFFFFu) != 0u;
}

// lp vec k covers floats j=4k..4k+3 (lp row k>>3); matching data floats at
// j + (k>>3) + 34 (cols 1..32 of row (k>>3)+1). Rows past len are all-NaN.
// Clamped loads (k >= nvec -> vec nvec-1) are wave-uniform broadcasts, L1-hot.
template <int D>
__device__ __forceinline__ void issue_loads(const float* __restrict__ lpbase,
                                            const float* __restrict__ dbase,
                                            int k0, int nvec, f4* lpv, f4* dv) {
    #pragma unroll
    for (int u = 0; u < D; ++u) {
        int k  = k0 + u * 256;
        int kc = k < nvec ? k : nvec - 1;
        int j  = kc * 4;
        int sr = kc >> 3;
        lpv[u] = *reinterpret_cast<const f4*>(lpbase + j);
        dv[u]  = *reinterpret_cast<const f4u*>(dbase + j + sr + 34);
    }
}

// NaN-masked accumulate; counts valid rows via the (k&7)==0 vec's elem 0.
template <int D>
__device__ __forceinline__ void accum(const f4* lpv, const f4* dv,
                                      int k0, int nvec, float& acc, int& cnt) {
    #pragma unroll
    for (int u = 0; u < D; ++u) {
        int k = k0 + u * 256;
        if (k < nvec) {
            #pragma unroll
            for (int i = 0; i < 4; ++i) {
                float de = dv[u][i];
                float df = lpv[u][i] - de;
                if (is_nan_bits(de)) df = 0.0f;
                acc = fmaf(df, df, acc);
            }
            if ((k & 7) == 0 && !is_nan_bits(dv[u][0])) cnt++;
        }
    }
}

__global__ __launch_bounds__(256, 4)
void fused_kernel(const float* __restrict__ long_pred,
                  const float* __restrict__ surv_pred,
                  const float* __restrict__ data,
                  const uint32_t* __restrict__ event_words,
                  const float* __restrict__ event_time,
                  const float* __restrict__ time_range,
                  double* __restrict__ ll_part,
                  int* __restrict__ lenm1,
                  double* __restrict__ nll_part) {
    const int tid  = threadIdx.x;
    const int blk  = blockIdx.x;
    const int wib  = tid >> 6;
    const int lane = tid & 63;

    if (blk < NLLB) {
        // ---------------- survival NLL: 4 batch rows per block ---------------
        // event storage detect (scan exactly B bytes: safe in all layouts)
        __shared__ int s_gt1, s_oddnz;
        if (tid == 0) { s_gt1 = 0; s_oddnz = 0; }
        __syncthreads();
        int gt1 = 0, oddnz = 0;
        for (int i = tid; i < B / 4; i += 256) {
            uint32_t w = event_words[i];
            if (w > 1u) gt1 = 1;
            if ((i & 1) && w != 0u) oddnz = 1;
        }
        if (gt1)   atomicOr(&s_gt1, 1);
        if (oddnz) atomicOr(&s_oddnz, 1);
        __syncthreads();
        const int mode = s_gt1 ? 1 : (s_oddnz ? 0 : 2);  // 1=u8, 0=i32, 2=i64

        const int b = blk * 4 + wib;
        float sv = (lane < T) ? surv_pred[b * T + lane] : 0.0f;
        float tr = (lane < T) ? time_range[lane] : 0.0f;
        float et = event_time[b];

        // searchsorted(time_range, et, 'right') - 1
        unsigned long long bal = __ballot(lane < T && tr <= et);
        int idx = (int)__popcll(bal) - 1;

        // tail = sum_{t >= idx+1} surv_pred[b,t]
        float tval = (lane < T && lane >= idx + 1) ? sv : 0.0f;
        for (int off = 32; off > 0; off >>= 1) tval += __shfl_down(tval, off);

        int   idx_c  = idx < 0 ? 0 : idx;
        float at_idx = __shfl(sv, idx_c);

        bool ev;
        if (mode == 1)      ev = ((const unsigned char*)event_words)[b] != 0;
        else if (mode == 2) ev = ((const int*)event_words)[2 * b] != 0;
        else                ev = ((const int*)event_words)[b] != 0;

        __shared__ double s_n[4];
        if (lane == 0) {
            float f = ev ? at_idx : ((idx + 1 < T) ? tval : 0.0f);
            if (f == 0.0f) f = (float)EPSV;
            s_n[wib] = -(double)logf(f);
        }
        __syncthreads();
        if (tid == 0) nll_part[blk] = s_n[0] + s_n[1] + s_n[2] + s_n[3];
    } else {
        // ---------------- longitudinal sweep: one batch row per block --------
        const int b = blk - NLLB;
        const float* __restrict__ dbase  = data      + (size_t)b * (S * V);
        const float* __restrict__ lpbase = long_pred + (size_t)b * (S * (V - 1));

        // one probe round: threads 0..49 test row 4t+3 col 1 (prefix validity)
        int valid = 0;
        if (tid < 50) valid = !is_nan_bits(dbase[(size_t)(4 * tid + 3) * V + 1]);
        const int c1 = __syncthreads_count(valid);       // = #valid probes
        const int bound_rows = min(4 * c1 + 2, S - 1);   // >= len-1, <= len+2
        const int nvec = bound_rows * 8;                 // <= 1592

        // branchless full-depth issue: 14 dwordx4 loads clustered before any
        // consume (sched_group_barrier pins VMEM_READ group) -> real MLP.
        f4 lpv[7], dv[7];
        issue_loads<7>(lpbase, dbase, tid, nvec, lpv, dv);
        __builtin_amdgcn_sched_group_barrier(0x020, 14, 0);  // 14 VMEM reads

        float acc = 0.0f;
        int   cnt = 0;
        accum<7>(lpv, dv, tid, nvec, acc, cnt);

        for (int off = 32; off > 0; off >>= 1) {
            acc += __shfl_down(acc, off);
            cnt += __shfl_down(cnt, off);
        }
        __shared__ float s_red[4];
        __shared__ int   s_cnt[4];
        if (lane == 0) { s_red[wib] = acc; s_cnt[wib] = cnt; }
        __syncthreads();
        if (tid == 0) {
            ll_part[b] = (double)s_red[0] + (double)s_red[1]
                       + (double)s_red[2] + (double)s_red[3];
            lenm1[b]   = s_cnt[0] + s_cnt[1] + s_cnt[2] + s_cnt[3];
        }
    }
}

__global__ __launch_bounds__(256)
void finalize_kernel(const double* __restrict__ ll_part,
                     const int* __restrict__ lenm1,
                     const double* __restrict__ nll_part,
                     float* __restrict__ out) {
    const int tid = threadIdx.x;
    double ls = 0.0, ns = 0.0;
    long long cs = 0;
    for (int i = tid; i < B; i += 256)    { ls += ll_part[i]; cs += lenm1[i]; }
    for (int i = tid; i < NLLB; i += 256) ns += nll_part[i];

    for (int off = 32; off > 0; off >>= 1) {
        ls += __shfl_down(ls, off);
        ns += __shfl_down(ns, off);
        cs += __shfl_down(cs, off);
    }
    __shared__ double    sl[4], sn[4];
    __shared__ long long sc[4];
    const int wib = tid >> 6, lane = tid & 63;
    if (lane == 0) { sl[wib] = ls; sn[wib] = ns; sc[wib] = cs; }
    __syncthreads();
    if (tid == 0) {
        double L = 0.0, N = 0.0;
        long long C = 0;
        for (int i = 0; i < 4; ++i) { L += sl[i]; N += sn[i]; C += sc[i]; }
        double denom = (double)C * (double)(V - 1);
        out[0] = (float)(N / (double)B + L / denom);
    }
}

extern "C" void kernel_launch(void* const* d_in, const int* in_sizes, int n_in,
                              void* d_out, int out_size, void* d_ws, size_t ws_size,
                              hipStream_t stream) {
    const float* long_pred  = (const float*)d_in[0];
    const float* surv_pred  = (const float*)d_in[1];
    const float* data       = (const float*)d_in[2];
    const void*  event      = d_in[3];
    const float* event_time = (const float*)d_in[4];
    const float* time_range = (const float*)d_in[5];
    float* out = (float*)d_out;

    double* ll_part  = (double*)d_ws;
    int*    lenm1    = (int*)((char*)d_ws + 32768);
    double* nll_part = (double*)((char*)d_ws + 49152);

    fused_kernel<<<GRID, 256, 0, stream>>>(
        long_pred, surv_pred, data, (const uint32_t*)event, event_time,
        time_range, ll_part, lenm1, nll_part);
    finalize_kernel<<<1, 256, 0, stream>>>(ll_part, lenm1, nll_part, out);
}